// Round 3
// baseline (325.700 us; speedup 1.0000x reference)
//
#include <hip/hip_runtime.h>
#include <math.h>

typedef _Float16 f16x8 __attribute__((ext_vector_type(8)));
typedef _Float16 f16x4 __attribute__((ext_vector_type(4)));
typedef float f32x4 __attribute__((ext_vector_type(4)));

__device__ __forceinline__ void async_copy16(const void* g, void* l) {
    __builtin_amdgcn_global_load_lds(
        (const __attribute__((address_space(1))) void*)g,
        (__attribute__((address_space(3))) void*)l, 16, 0, 0);
}

// ---------------- cast x (fp32) -> f16 ----------------
__global__ __launch_bounds__(256) void cast_f32_f16_kernel(
    const float4* __restrict__ in, f16x4* __restrict__ out) {
    int i = blockIdx.x * 256 + threadIdx.x;
    float4 v = in[i];
    f16x4 o;
    o[0] = (_Float16)v.x; o[1] = (_Float16)v.y;
    o[2] = (_Float16)v.z; o[3] = (_Float16)v.w;
    out[i] = o;
}

// ---------------- fused TT-core -> dense weight builds ----------------
// W0t[n][kin] f16, n=(o*16+p)*16+q (4096), kin=i*128+j*8+k (1024)
// block = (o,p), 256 blocks. G[q][r][j][k] (fixed p) in LDS.
__global__ __launch_bounds__(256) void build_W0t_fused(
    const float* __restrict__ c0a, const float* __restrict__ c0b,
    const float* __restrict__ c0c, _Float16* __restrict__ W0t) {
    __shared__ float G[16384];  // [q16][r8][j16][k8]
    const int o = blockIdx.x >> 4, p = blockIdx.x & 15;
    const int t = threadIdx.x;
    // stage A: G[q][r][j][k] = sum_s c0b[r,j,p,s] * c0c[s,k,q]
#pragma unroll
    for (int n = 0; n < 64; ++n) {
        int idx = t + 256 * n;
        int k = idx & 7, j = (idx >> 3) & 15, r = (idx >> 7) & 7, q = idx >> 10;
        float s = 0.f;
#pragma unroll
        for (int ss = 0; ss < 8; ++ss)
            s += c0b[((r * 16 + j) * 16 + p) * 8 + ss] * c0c[(ss * 8 + k) * 16 + q];
        G[idx] = s;
    }
    __syncthreads();
    // stage B: W0t[(o,p,q)][i,j,k] = sum_r c0a[i,o,r] * G[q][r][j][k]
    const int i = t >> 5, j = (t >> 1) & 15, kq = t & 1;  // col base = 4*t
    float a[8];
#pragma unroll
    for (int r = 0; r < 8; ++r) a[r] = c0a[(i * 16 + o) * 8 + r];
    const float4* G4 = (const float4*)G;
#pragma unroll
    for (int q = 0; q < 16; ++q) {
        float4 acc = {0.f, 0.f, 0.f, 0.f};
#pragma unroll
        for (int r = 0; r < 8; ++r) {
            float4 g = G4[q * 256 + r * 32 + j * 2 + kq];
            acc.x += a[r] * g.x; acc.y += a[r] * g.y;
            acc.z += a[r] * g.z; acc.w += a[r] * g.w;
        }
        f16x4 h4;
        h4[0] = (_Float16)acc.x; h4[1] = (_Float16)acc.y;
        h4[2] = (_Float16)acc.z; h4[3] = (_Float16)acc.w;
        *(f16x4*)(W0t + (size_t)((o * 16 + p) * 16 + q) * 1024 + t * 4) = h4;
    }
}

// W1t[n][kin] f16, n=(o*16+p)*8+q (1024), kin=i*256+j*16+k (4096)
// block = (o,p), o<8,p<16 -> 128 blocks. G[q8][r8][j16][k16] in LDS.
__global__ __launch_bounds__(256) void build_W1t_fused(
    const float* __restrict__ c1a, const float* __restrict__ c1b,
    const float* __restrict__ c1c, _Float16* __restrict__ W1t) {
    __shared__ float G[16384];  // [q8][r8][j16][k16]
    const int o = blockIdx.x >> 4, p = blockIdx.x & 15;
    const int t = threadIdx.x;
    // stage A: G[q][r][j][k] = sum_s c1b[r,j,p,s] * c1c[s,k,q]
#pragma unroll
    for (int n = 0; n < 64; ++n) {
        int idx = t + 256 * n;
        int k = idx & 15, j = (idx >> 4) & 15, r = (idx >> 8) & 7, q = idx >> 11;
        float s = 0.f;
#pragma unroll
        for (int ss = 0; ss < 8; ++ss)
            s += c1b[((r * 16 + j) * 16 + p) * 8 + ss] * c1c[(ss * 16 + k) * 8 + q];
        G[idx] = s;
    }
    __syncthreads();
    // stage B: W1t[(o,p,q)][i,j,k] = sum_r c1a[i,o,r] * G[q][r][j][k]
    const int ig = t >> 6, j = (t >> 2) & 15, kq = t & 3;
    float a[4][8];
#pragma unroll
    for (int ii = 0; ii < 4; ++ii)
#pragma unroll
        for (int r = 0; r < 8; ++r) a[ii][r] = c1a[((ig * 4 + ii) * 8 + o) * 8 + r];
    const float4* G4 = (const float4*)G;
#pragma unroll
    for (int q = 0; q < 8; ++q) {
        float4 acc[4] = {{0,0,0,0},{0,0,0,0},{0,0,0,0},{0,0,0,0}};
#pragma unroll
        for (int r = 0; r < 8; ++r) {
            float4 g = G4[q * 512 + r * 64 + j * 4 + kq];
#pragma unroll
            for (int ii = 0; ii < 4; ++ii) {
                acc[ii].x += a[ii][r] * g.x; acc[ii].y += a[ii][r] * g.y;
                acc[ii].z += a[ii][r] * g.z; acc[ii].w += a[ii][r] * g.w;
            }
        }
        const size_t rowbase = (size_t)((o * 16 + p) * 8 + q) * 4096;
#pragma unroll
        for (int ii = 0; ii < 4; ++ii) {
            f16x4 h4;
            h4[0] = (_Float16)acc[ii].x; h4[1] = (_Float16)acc[ii].y;
            h4[2] = (_Float16)acc[ii].z; h4[3] = (_Float16)acc[ii].w;
            *(f16x4*)(W1t + rowbase + (ig * 4 + ii) * 256 + j * 16 + kq * 4) = h4;
        }
    }
}

// ---------------- GEMM: C = A(MxK) * Bt(NxK)^T ----------------
// XCD-aware 8x8 super-tile swizzle: blocks f with f&7==x land on XCD x
// (round-robin heuristic); each XCD runs an 8-row x 8-col square of tiles
// in approx k-lockstep -> A/B k-slices reused 8x from its 4MB L2.
// Requires gridDim.x == 64*nby (nbx=64 rows), nby multiple of 8 or ==8.
template <int OUTMODE>
__global__ __launch_bounds__(256) void gemm_bt_kernel(
    const _Float16* __restrict__ A, const _Float16* __restrict__ Bt,
    const float* __restrict__ bias, void* __restrict__ Cout,
    int M, int N, int K) {
    constexpr int BK = 32;
    __shared__ alignas(16) _Float16 sA[128 * BK];
    __shared__ alignas(16) _Float16 sB[128 * BK];

    const int f = blockIdx.x;
    const int xcd = f & 7, s = f >> 3, g = s >> 6, u = s & 63;
    const int m0 = (xcd * 8 + (u >> 3)) * 128;
    const int n0 = (g * 8 + (u & 7)) * 128;

    const int t = threadIdx.x;
    const int lane = t & 63;
    const int w = t >> 6;
    const int wm = (w & 1) * 64;
    const int wn = (w >> 1) * 64;
    const int lm = lane & 15;
    const int lq = lane >> 4;
    const int kxor = lq ^ ((lm >> 1) & 3);  // de-swizzle for fragment reads

    f32x4 acc[4][4] = {};

    const int srow = t >> 2;                          // 0..63
    const int sk = ((t & 3) ^ ((t >> 3) & 3)) * 8;    // swizzled k-chunk to fetch
    const _Float16* gA = A + (size_t)(m0 + srow) * K + sk;
    const _Float16* gB = Bt + (size_t)(n0 + srow) * K + sk;
    _Float16* lA = sA + srow * BK + (t & 3) * 8;  // dst = wave base + lane*16 (contiguous)
    _Float16* lB = sB + srow * BK + (t & 3) * 8;
    const size_t rowskip = (size_t)64 * K;

    for (int k0 = 0; k0 < K; k0 += BK) {
        async_copy16(gA + k0, lA);
        async_copy16(gA + k0 + rowskip, lA + 64 * BK);
        async_copy16(gB + k0, lB);
        async_copy16(gB + k0 + rowskip, lB + 64 * BK);
        __syncthreads();

        f16x8 af[4], bf[4];
#pragma unroll
        for (int i = 0; i < 4; ++i) {
            af[i] = *(const f16x8*)(sA + (wm + i * 16 + lm) * BK + kxor * 8);
            bf[i] = *(const f16x8*)(sB + (wn + i * 16 + lm) * BK + kxor * 8);
        }
#pragma unroll
        for (int i = 0; i < 4; ++i)
#pragma unroll
            for (int j = 0; j < 4; ++j)
                acc[i][j] = __builtin_amdgcn_mfma_f32_16x16x32_f16(af[i], bf[j], acc[i][j], 0, 0, 0);
        __syncthreads();
    }

    if (OUTMODE == 1) {
        _Float16* C = (_Float16*)Cout;
#pragma unroll
        for (int i = 0; i < 4; ++i)
#pragma unroll
            for (int j = 0; j < 4; ++j) {
                int col = n0 + wn + j * 16 + lm;
                float bv = bias[col];
#pragma unroll
                for (int r = 0; r < 4; ++r) {
                    int row = m0 + wm + i * 16 + lq * 4 + r;
                    float v = acc[i][j][r] + bv;
                    // tanh-form GELU via exp2+rcp (max dev from erf form ~3e-4)
                    float uu = v * (0.7978845608028654f + 0.0356774081363001f * v * v);
                    float e = __builtin_amdgcn_exp2f(uu * 2.8853900817779268f);  // exp(2u)
                    float rc = __builtin_amdgcn_rcpf(e + 1.0f);
                    C[(size_t)row * N + col] = (_Float16)(v * (1.0f - rc));
                }
            }
    } else {
        float* C = (float*)Cout;
#pragma unroll
        for (int i = 0; i < 4; ++i)
#pragma unroll
            for (int j = 0; j < 4; ++j) {
                int col = n0 + wn + j * 16 + lm;
                float bv = bias[col];
#pragma unroll
                for (int r = 0; r < 4; ++r) {
                    int row = m0 + wm + i * 16 + lq * 4 + r;
                    C[(size_t)row * N + col] = acc[i][j][r] + bv;
                }
            }
    }
}

extern "C" void kernel_launch(void* const* d_in, const int* in_sizes, int n_in,
                              void* d_out, int out_size, void* d_ws, size_t ws_size,
                              hipStream_t stream) {
    const float* x   = (const float*)d_in[0];
    const float* c0a = (const float*)d_in[1];
    const float* c0b = (const float*)d_in[2];
    const float* c0c = (const float*)d_in[3];
    const float* b0  = (const float*)d_in[4];
    const float* c1a = (const float*)d_in[5];
    const float* c1b = (const float*)d_in[6];
    const float* c1c = (const float*)d_in[7];
    const float* b1  = (const float*)d_in[8];
    float* out = (float*)d_out;

    char* ws = (char*)d_ws;
    _Float16* xh  = (_Float16*)(ws);                          // 16 MB
    _Float16* W0t = (_Float16*)(ws + (size_t)(16u << 20));    //  8 MB
    _Float16* W1t = (_Float16*)(ws + (size_t)(24u << 20));    //  8 MB
    _Float16* h   = (_Float16*)(ws + (size_t)(32u << 20));    // 64 MB (8192x4096 f16)

    // 1) cast x -> f16
    cast_f32_f16_kernel<<<dim3(8192), dim3(256), 0, stream>>>((const float4*)x, (f16x4*)xh);
    // 2) fused TT-core pre-contractions -> dense transposed weights (N x K, f16)
    build_W0t_fused<<<dim3(256), dim3(256), 0, stream>>>(c0a, c0b, c0c, W0t);
    build_W1t_fused<<<dim3(128), dim3(256), 0, stream>>>(c1a, c1b, c1c, W1t);
    // 3) h = gelu(x @ W0 + b0)   M=8192 N=4096 K=1024  (grid 64x32 swizzled)
    gemm_bt_kernel<1><<<dim3(2048), dim3(256), 0, stream>>>(xh, W0t, b0, (void*)h, 8192, 4096, 1024);
    // 4) out = h @ W1 + b1       M=8192 N=1024 K=4096  (grid 64x8 swizzled)
    gemm_bt_kernel<0><<<dim3(512), dim3(256), 0, stream>>>(h, W1t, b1, (void*)out, 8192, 1024, 4096);
}